// Round 19
// baseline (2851.525 us; speedup 1.0000x reference)
//
#include <hip/hip_runtime.h>
#include <math.h>

#define B_ROWS 32768
#define DIM    1024
#define PADA   268   // A LDS stride: 256 cols + row-shift (<=12); 268 mod 32 = 12
#define PADB   140   // B LDS stride: 128 cols + row-shift;       140 mod 32 = 12

// Numerics contract (verified r10-r18, absmax 0.0): BLIS sgemm, KC=512.
// Per C element: p1 = serial ascending FMA chain k=0..511, p2 = k=512..1023,
// C = fl(p1+p2).
//
// r18 result: bank conflicts == 0, VALUBusy 53% -> limiter is the LDS
// read-issue budget (4 b128/kk for 64 FMA = 67% cap). This round: 16x8
// register tile (6 b128/kk for 128 FMA = 89% cap) via SPLIT-K:
//   kernel a: p1 chain (k<512) -> f32 partial (stored in the sgn region,
//             which is scratch until k5-final overwrites it)
//   kernel b: p2 chain + fold fl(p1+p2) + epilogue
// 256-thread blocks, 52KB LDS -> 2 blocks/CU co-resident (cross-block
// phase overlap). Bank layout: both-sides row-shift col' = col+4*(krow>>3),
// strides ≡ 12 mod 32 -> reads <=2-way, writes <=2-way (free per m136).

struct FragT { float4 a[8]; float4 b[4]; };

__device__ __forceinline__ void loadT(const float* pA, const float* pB, FragT& f) {
#pragma unroll
    for (int i = 0; i < 8; ++i) f.a[i] = *(const float4*)(pA + (size_t)(32 * i) * DIM);
#pragma unroll
    for (int i = 0; i < 4; ++i) f.b[i] = *(const float4*)(pB + (size_t)(32 * i) * DIM);
}

__device__ __forceinline__ void storeT(const FragT& f, float (*As)[PADA], float (*Bs)[PADB],
                                       int kq, int r0) {
    const int c0 = kq * 4, sh = 4 * (kq >> 1);   // sh = 4*((4kq+j)>>3), j<4
#pragma unroll
    for (int i = 0; i < 8; ++i) {
        const int col = r0 + 32 * i + sh;
        As[c0 + 0][col] = f.a[i].x; As[c0 + 1][col] = f.a[i].y;
        As[c0 + 2][col] = f.a[i].z; As[c0 + 3][col] = f.a[i].w;
    }
#pragma unroll
    for (int i = 0; i < 4; ++i) {
        const int col = r0 + 32 * i + sh;
        Bs[c0 + 0][col] = f.b[i].x; Bs[c0 + 1][col] = f.b[i].y;
        Bs[c0 + 2][col] = f.b[i].z; Bs[c0 + 3][col] = f.b[i].w;
    }
}

__device__ __forceinline__ void compute16x8(const float (*As)[PADA], const float (*Bs)[PADB],
                                            int tx, int ty, float (&acc)[16][8]) {
#pragma unroll
    for (int kk = 0; kk < 32; ++kk) {
        const int sh = 4 * (kk >> 3);            // compile-time per unrolled kk
        const float4 A0 = *(const float4*)&As[kk][4 * ty + sh];
        const float4 A1 = *(const float4*)&As[kk][4 * ty + 64 + sh];
        const float4 A2 = *(const float4*)&As[kk][4 * ty + 128 + sh];
        const float4 A3 = *(const float4*)&As[kk][4 * ty + 192 + sh];
        const float4 B0 = *(const float4*)&Bs[kk][4 * tx + sh];
        const float4 B1 = *(const float4*)&Bs[kk][4 * tx + 64 + sh];
        const float a[16] = {A0.x, A0.y, A0.z, A0.w, A1.x, A1.y, A1.z, A1.w,
                             A2.x, A2.y, A2.z, A2.w, A3.x, A3.y, A3.z, A3.w};
        const float b[8]  = {B0.x, B0.y, B0.z, B0.w, B1.x, B1.y, B1.z, B1.w};
#pragma unroll
        for (int i = 0; i < 16; ++i)
#pragma unroll
            for (int j = 0; j < 8; ++j)
                acc[i][j] = fmaf(a[i], b[j], acc[i][j]);
    }
}

// staged K-half loop, A@B^T form (A,B row-major [rows][k])
__device__ __forceinline__ void runT(const float* Ab, const float* Bb, int m0, int n0,
                                     int koff, int tid,
                                     float (*As)[PADA], float (*Bs)[PADB],
                                     float (&acc)[16][8]) {
    const int tx = tid & 15, ty = tid >> 4, kq = tid & 7, r0 = tid >> 3;
    const float* pA = Ab + (size_t)(m0 + r0) * DIM + koff + kq * 4;
    const float* pB = Bb + (size_t)(n0 + r0) * DIM + koff + kq * 4;
    FragT f;
    loadT(pA, pB, f);
    for (int t = 0; t < 16; ++t) {
        __syncthreads();
        storeT(f, As, Bs, kq, r0);
        __syncthreads();
        if (t < 15) loadT(pA + (t + 1) * 32, pB + (t + 1) * 32, f);
        compute16x8(As, Bs, tx, ty, acc);
    }
}

// staged K-half loop, gather-A (centroids via idx8) @ Pi (not transposed)
__device__ __forceinline__ void runG(const unsigned char* idxb, const float* Pi,
                                     const float* clut, int m0, int n0, int koff, int tid,
                                     float (*As)[PADA], float (*Bs)[PADB],
                                     float (&acc)[16][8]) {
    const int tx = tid & 15, ty = tid >> 4, kq = tid & 7, r0 = tid >> 3;
    const int nq = tid & 31, kr0 = tid >> 5;
    const unsigned char* pA = idxb + (size_t)(m0 + r0) * DIM + koff + kq * 4;
    const float*         pB = Pi + (size_t)(koff + kr0) * DIM + n0 + nq * 4;
    uchar4 ka[8]; float4 kb[4];
#pragma unroll
    for (int i = 0; i < 8; ++i) ka[i] = *(const uchar4*)(pA + (size_t)(32 * i) * DIM);
#pragma unroll
    for (int i = 0; i < 4; ++i) kb[i] = *(const float4*)(pB + (size_t)(8 * i) * DIM);
    for (int t = 0; t < 16; ++t) {
        __syncthreads();
        {
            const int c0 = kq * 4, sh = 4 * (kq >> 1);
#pragma unroll
            for (int i = 0; i < 8; ++i) {
                const int col = r0 + 32 * i + sh;
                As[c0 + 0][col] = clut[ka[i].x]; As[c0 + 1][col] = clut[ka[i].y];
                As[c0 + 2][col] = clut[ka[i].z]; As[c0 + 3][col] = clut[ka[i].w];
            }
#pragma unroll
            for (int i = 0; i < 4; ++i)
                *(float4*)&Bs[kr0 + 8 * i][nq * 4 + 4 * i] = kb[i];   // col' = n + 4*(krow>>3)
        }
        __syncthreads();
        if (t < 15) {
#pragma unroll
            for (int i = 0; i < 8; ++i)
                ka[i] = *(const uchar4*)(pA + (t + 1) * 32 + (size_t)(32 * i) * DIM);
#pragma unroll
            for (int i = 0; i < 4; ++i)
                kb[i] = *(const float4*)(pB + (size_t)((t + 1) * 32 + 8 * i) * DIM);
        }
        compute16x8(As, Bs, tx, ty, acc);
    }
}

// ---------------- kT_part: partial p1 (k<512), A@B^T -> part ----------------
__global__ __launch_bounds__(256) void kT_part(
    const float* __restrict__ A, const float* __restrict__ B, float* __restrict__ part)
{
    __shared__ float As[32][PADA];
    __shared__ float Bs[32][PADB];
    const int tid = threadIdx.x, tx = tid & 15, ty = tid >> 4;
    const int m0 = blockIdx.y * 256, n0 = blockIdx.x * 128;
    float acc[16][8] = {};
    runT(A, B, m0, n0, 0, tid, As, Bs, acc);
#pragma unroll
    for (int i = 0; i < 16; ++i) {
        const int row = m0 + 64 * (i >> 2) + 4 * ty + (i & 3);
        const size_t o = (size_t)row * DIM + n0 + tx * 4;
        *(float4*)&part[o]      = make_float4(acc[i][0], acc[i][1], acc[i][2], acc[i][3]);
        *(float4*)&part[o + 64] = make_float4(acc[i][4], acc[i][5], acc[i][6], acc[i][7]);
    }
}

// ---------------- k1_final: p2 + fold + argmin -> idxf, idx8 ----------------
__global__ __launch_bounds__(256) void k1_final(
    const float* __restrict__ X, const float* __restrict__ Pi, const float* __restrict__ C,
    const float* __restrict__ part, float* __restrict__ idxf, unsigned char* __restrict__ idx8)
{
    __shared__ float As[32][PADA];
    __shared__ float Bs[32][PADB];
    const int tid = threadIdx.x, tx = tid & 15, ty = tid >> 4;
    const int m0 = blockIdx.y * 256, n0 = blockIdx.x * 128;
    float acc[16][8] = {};
    runT(X, Pi, m0, n0, 512, tid, As, Bs, acc);
    float c8[8];
#pragma unroll
    for (int t = 0; t < 8; ++t) c8[t] = C[t];
#pragma unroll
    for (int i = 0; i < 16; ++i) {
        const int row = m0 + 64 * (i >> 2) + 4 * ty + (i & 3);
        const size_t o = (size_t)row * DIM + n0 + tx * 4;
        const float4 p1l = *(const float4*)&part[o];
        const float4 p1h = *(const float4*)&part[o + 64];
        const float y[8] = {p1l.x + acc[i][0], p1l.y + acc[i][1], p1l.z + acc[i][2], p1l.w + acc[i][3],
                            p1h.x + acc[i][4], p1h.y + acc[i][5], p1h.z + acc[i][6], p1h.w + acc[i][7]};
        float fv[8]; unsigned char bv[8];
#pragma unroll
        for (int j = 0; j < 8; ++j) {
            float best = fabsf(y[j] - c8[0]); int bi = 0;
#pragma unroll
            for (int t2 = 1; t2 < 8; ++t2) {
                const float d = fabsf(y[j] - c8[t2]);
                if (d < best) { best = d; bi = t2; }   // strict <: np first-min tie rule
            }
            fv[j] = (float)bi; bv[j] = (unsigned char)bi;
        }
        *(float4*)&idxf[o]      = make_float4(fv[0], fv[1], fv[2], fv[3]);
        *(float4*)&idxf[o + 64] = make_float4(fv[4], fv[5], fv[6], fv[7]);
        *(uchar4*)&idx8[o]      = make_uchar4(bv[0], bv[1], bv[2], bv[3]);
        *(uchar4*)&idx8[o + 64] = make_uchar4(bv[4], bv[5], bv[6], bv[7]);
    }
}

// ---------------- k3_part: partial p1 of xhat = yhat @ Pi ----------------
__global__ __launch_bounds__(256) void k3_part(
    const unsigned char* __restrict__ idx8, const float* __restrict__ Pi,
    const float* __restrict__ C, float* __restrict__ part)
{
    __shared__ float As[32][PADA];
    __shared__ float Bs[32][PADB];
    __shared__ float clut[8];
    const int tid = threadIdx.x, tx = tid & 15, ty = tid >> 4;
    const int m0 = blockIdx.y * 256, n0 = blockIdx.x * 128;
    if (tid < 8) clut[tid] = C[tid];
    float acc[16][8] = {};
    runG(idx8, Pi, clut, m0, n0, 0, tid, As, Bs, acc);
#pragma unroll
    for (int i = 0; i < 16; ++i) {
        const int row = m0 + 64 * (i >> 2) + 4 * ty + (i & 3);
        const size_t o = (size_t)row * DIM + n0 + tx * 4;
        *(float4*)&part[o]      = make_float4(acc[i][0], acc[i][1], acc[i][2], acc[i][3]);
        *(float4*)&part[o + 64] = make_float4(acc[i][4], acc[i][5], acc[i][6], acc[i][7]);
    }
}

// ---------------- k3_final: p2 + fold; R = X - xhat; norm partials ----------------
__global__ __launch_bounds__(256) void k3_final(
    const float* __restrict__ X, const float* __restrict__ Pi, const float* __restrict__ C,
    const unsigned char* __restrict__ idx8, const float* __restrict__ part,
    float* __restrict__ R, double* __restrict__ nrm2)
{
    __shared__ float As[32][PADA];
    __shared__ float Bs[32][PADB];
    __shared__ float clut[8];
    const int tid = threadIdx.x, tx = tid & 15, ty = tid >> 4;
    const int m0 = blockIdx.y * 256, n0 = blockIdx.x * 128;
    if (tid < 8) clut[tid] = C[tid];
    float acc[16][8] = {};
    runG(idx8, Pi, clut, m0, n0, 512, tid, As, Bs, acc);
#pragma unroll
    for (int i = 0; i < 16; ++i) {
        const int row = m0 + 64 * (i >> 2) + 4 * ty + (i & 3);
        const size_t o = (size_t)row * DIM + n0 + tx * 4;
        const float4 p1l = *(const float4*)&part[o];
        const float4 p1h = *(const float4*)&part[o + 64];
        const float4 x0 = *(const float4*)&X[o];
        const float4 x1 = *(const float4*)&X[o + 64];
        float rv[8];
        rv[0] = x0.x - (p1l.x + acc[i][0]); rv[1] = x0.y - (p1l.y + acc[i][1]);
        rv[2] = x0.z - (p1l.z + acc[i][2]); rv[3] = x0.w - (p1l.w + acc[i][3]);
        rv[4] = x1.x - (p1h.x + acc[i][4]); rv[5] = x1.y - (p1h.y + acc[i][5]);
        rv[6] = x1.z - (p1h.z + acc[i][6]); rv[7] = x1.w - (p1h.w + acc[i][7]);
        *(float4*)&R[o]      = make_float4(rv[0], rv[1], rv[2], rv[3]);
        *(float4*)&R[o + 64] = make_float4(rv[4], rv[5], rv[6], rv[7]);
        double s = 0.0;
#pragma unroll
        for (int j = 0; j < 8; ++j) s = fma((double)rv[j], (double)rv[j], s);
#pragma unroll
        for (int mask = 1; mask < 16; mask <<= 1) s += __shfl_xor(s, mask, 16);
        if (tx == 0) atomicAdd(&nrm2[row], s);
    }
}

// ---------------- k5_final: p2 + fold + sign (partial lives in SAME buffer) ----------------
__global__ __launch_bounds__(256) void k5_final(
    const float* __restrict__ R, const float* __restrict__ S, float* psgn)
{
    __shared__ float As[32][PADA];
    __shared__ float Bs[32][PADB];
    const int tid = threadIdx.x, tx = tid & 15, ty = tid >> 4;
    const int m0 = blockIdx.y * 256, n0 = blockIdx.x * 128;
    float acc[16][8] = {};
    runT(R, S, m0, n0, 512, tid, As, Bs, acc);
#pragma unroll
    for (int i = 0; i < 16; ++i) {
        const int row = m0 + 64 * (i >> 2) + 4 * ty + (i & 3);
        const size_t o = (size_t)row * DIM + n0 + tx * 4;
        const float4 p1l = *(const float4*)&psgn[o];       // read partial
        const float4 p1h = *(const float4*)&psgn[o + 64];
        const float p[8] = {p1l.x + acc[i][0], p1l.y + acc[i][1], p1l.z + acc[i][2], p1l.w + acc[i][3],
                            p1h.x + acc[i][4], p1h.y + acc[i][5], p1h.z + acc[i][6], p1h.w + acc[i][7]};
        *(float4*)&psgn[o]      = make_float4((p[0] >= 0.f) ? 1.f : -1.f, (p[1] >= 0.f) ? 1.f : -1.f,
                                              (p[2] >= 0.f) ? 1.f : -1.f, (p[3] >= 0.f) ? 1.f : -1.f);
        *(float4*)&psgn[o + 64] = make_float4((p[4] >= 0.f) ? 1.f : -1.f, (p[5] >= 0.f) ? 1.f : -1.f,
                                              (p[6] >= 0.f) ? 1.f : -1.f, (p[7] >= 0.f) ? 1.f : -1.f);
    }
}

// ---------------- KN: norms = sqrt(nrm2) ----------------
__global__ __launch_bounds__(256) void kN_sqrt(const double* __restrict__ nrm2, float* __restrict__ nrm)
{
    const int i = blockIdx.x * 256 + threadIdx.x;
    if (i < B_ROWS) nrm[i] = (float)sqrt(nrm2[i]);
}

extern "C" void kernel_launch(void* const* d_in, const int* in_sizes, int n_in,
                              void* d_out, int out_size, void* d_ws, size_t ws_size,
                              hipStream_t stream) {
    const float* X  = (const float*)d_in[0];
    const float* Pi = (const float*)d_in[1];
    const float* C  = (const float*)d_in[2];
    const float* S  = (const float*)d_in[3];

    float* out  = (float*)d_out;
    float* idxf = out;                                   // B*D (index values)
    float* sgn  = out + (size_t)B_ROWS * DIM;            // B*D (+-1); ALSO split-K partial scratch
    float* nrm  = sgn + (size_t)B_ROWS * DIM;            // B

    char* ws = (char*)d_ws;
    float*         R    = (float*)ws;                                          // 128 MiB
    unsigned char* idx8 = (unsigned char*)(ws + (size_t)B_ROWS * DIM * 4);     //  32 MiB
    double*        nrm2 = (double*)(ws + (size_t)B_ROWS * DIM * 5);            // 256 KiB

    hipMemsetAsync(nrm2, 0, (size_t)B_ROWS * sizeof(double), stream);

    dim3 blk(256);
    dim3 gG(DIM / 128, B_ROWS / 256);                    // 8 x 128 = 1024 blocks

    kT_part <<<gG, blk, 0, stream>>>(X, Pi, sgn);                    // p1 of y
    k1_final<<<gG, blk, 0, stream>>>(X, Pi, C, sgn, idxf, idx8);     // y, argmin
    k3_part <<<gG, blk, 0, stream>>>(idx8, Pi, C, sgn);              // p1 of xhat
    k3_final<<<gG, blk, 0, stream>>>(X, Pi, C, idx8, sgn, R, nrm2);  // R, norm partials
    kN_sqrt <<<dim3(B_ROWS / 256), blk, 0, stream>>>(nrm2, nrm);
    kT_part <<<gG, blk, 0, stream>>>(R, S, sgn);                     // p1 of P
    k5_final<<<gG, blk, 0, stream>>>(R, S, sgn);                     // signs (in place)
}